// Round 7
// baseline (472.297 us; speedup 1.0000x reference)
//
#include <hip/hip_runtime.h>

typedef unsigned short u16;
typedef unsigned int   u32;
typedef __attribute__((ext_vector_type(8))) __bf16 bf16x8;
typedef __attribute__((ext_vector_type(4))) float   f32x4;

#define MROWS 16400     // 16 * 1025
#define NPADROWS 16512  // padded rows in bf16 buffers
#define KD 1024
#define MATEL ((size_t)NPADROWS * KD)   // elems per padded matrix
#define NT 32           // K-tiles of 32

__device__ __forceinline__ u16 f2b(float f) {
  union { float f; u32 u; } x; x.f = f;
  return (u16)((x.u + 0x7FFFu + ((x.u >> 16) & 1u)) >> 16);
}
__device__ __forceinline__ float b2f(u16 h) {
  union { u32 u; float f; } x; x.u = ((u32)h) << 16;
  return x.f;
}

__device__ __forceinline__ void gll16(const u16* g, u16* l) {
  __builtin_amdgcn_global_load_lds(
      (const __attribute__((address_space(1))) void*)g,
      (__attribute__((address_space(3))) void*)l, 16, 0, 0);
}

// ---------------------------------------------------------------------------
// Transpose + convert weights: W[k][n] f32 -> T[n][k] bf16  (z selects matrix)
// ---------------------------------------------------------------------------
__global__ __launch_bounds__(256) void k_wtrans(
    const float* __restrict__ W0, const float* __restrict__ W1,
    const float* __restrict__ W2, const float* __restrict__ W3,
    u16* __restrict__ T)
{
  __shared__ float tile[32][33];
  int z = blockIdx.z;
  const float* W = (z == 0) ? W0 : (z == 1) ? W1 : (z == 2) ? W2 : W3;
  u16* Tz = T + (size_t)z * KD * KD;
  int tx = threadIdx.x, ty = threadIdx.y;
  int k0 = blockIdx.x * 32, n0 = blockIdx.y * 32;
#pragma unroll
  for (int r = ty; r < 32; r += 8)
    tile[r][tx] = W[(size_t)(k0 + r) * KD + n0 + tx];
  __syncthreads();
#pragma unroll
  for (int r = ty; r < 32; r += 8)
    Tz[(size_t)(n0 + r) * KD + k0 + tx] = f2b(tile[tx][r]);
}

// ---------------------------------------------------------------------------
// 2-phase prefetch bf16 MFMA GEMM. 128x128 tile, BK=32, 4 waves 2x2,
// double-buffered LDS (32 KB), compiler-managed sync only (round-5 verified).
// A_FP32=true : A read as fp32 (q/k/v inputs), reg-staged + f2b + ds_write —
//               the convert pass is fused into staging (T14 issue-early /
//               write-late: loads for kt+1 land under tile kt's MFMA body).
// A_FP32=false: A read as bf16 via global_load_lds (out-proj path).
// B always bf16 via global_load_lds. LDS layout/fragment maps identical in
// both paths (byte-identical to the round-5/6 passing kernel).
// ---------------------------------------------------------------------------
template<bool A_FP32, bool OUT_FP32>
__global__ __launch_bounds__(256) void k_gemm(
    const void* __restrict__ A0v, const void* __restrict__ A1v,
    const void* __restrict__ A2v, const u16* __restrict__ Bt,
    u16* __restrict__ Cb, float* __restrict__ Cf,
    const float* __restrict__ bias, int nwg)
{
  __shared__ u16 lds[2 * 8192];   // buf: A[128][32] (4096) + B[128][32] (4096)

  int lin = blockIdx.x;
  int cpx = nwg >> 3;                       // nwg % 8 == 0 guaranteed
  int swz = (lin & 7) * cpx + (lin >> 3);   // bijective XCD swizzle
  int bn = swz & 7;
  int rest = swz >> 3;
  int bm = rest % 129;
  int z  = rest / 129;

  int t = threadIdx.x;
  int w = t >> 6, l = t & 63;
  int lrow = l & 15, kgrp = l >> 4;
  int wm = (w >> 1) * 64, wn = (w & 1) * 64;

  // ---- B staging (round-5 exact): wave w covers rows w*16..+15 per issue
  int srow = w * 16 + (l >> 2);
  int scol = (l & 3) * 8;
  const u16* gB  = Bt + (size_t)z * (1024 * 1024) + (size_t)(bn * 128 + srow) * KD + scol;
  const u16* gB2 = gB + (size_t)64 * KD;
  int dB0 = 4096 + w * 512;
  int dB1 = 6144 + w * 512;

  // ---- A staging
  // bf16 path (round-5 exact): gll16, same row/col map as B
  const u16* gA = nullptr; const u16* gA2 = nullptr;
  int dA0 = w * 512;
  int dA1 = 2048 + w * 512;
  // fp32 path: thread t owns row t>>1, k-half (t&1)*16 (16 floats -> 16 bf16)
  const float* gAf = nullptr;
  int awo = (t >> 1) * 32 + (t & 1) * 16;   // u16 offset of this thread's 16 bf16
  if constexpr (A_FP32) {
    const float* Af = (const float*)((z == 0) ? A0v : (z == 1) ? A1v : A2v);
    int ar = bm * 128 + (t >> 1);
    if (ar > MROWS - 1) ar = MROWS - 1;     // clamp tail rows
    gAf = Af + (size_t)ar * KD + (t & 1) * 16;
  } else {
    const u16* Ab = (const u16*)A0v;
    int ar = bm * 128 + srow;
    if (ar > NPADROWS - 1) ar = NPADROWS - 1;
    int ar2 = bm * 128 + 64 + srow;
    if (ar2 > NPADROWS - 1) ar2 = NPADROWS - 1;
    gA  = Ab + (size_t)ar * KD + scol;
    gA2 = Ab + (size_t)ar2 * KD + scol;
  }

  // fragment read offsets (u16 within buffer) — round-5 exact
  int aoff[4], boff[4];
#pragma unroll
  for (int fm = 0; fm < 4; ++fm)
    aoff[fm] = (wm + fm * 16 + lrow) * 32 + kgrp * 8;
#pragma unroll
  for (int fn = 0; fn < 4; ++fn)
    boff[fn] = 4096 + (wn + fn * 16 + lrow) * 32 + kgrp * 8;

  f32x4 acc[4][4] = {};

  // prologue: stage tile 0 into buffer 0, drain
  {
    u16* L = lds;
    if constexpr (A_FP32) {
      const float4 f0 = *(const float4*)(gAf + 0);
      const float4 f1 = *(const float4*)(gAf + 4);
      const float4 f2 = *(const float4*)(gAf + 8);
      const float4 f3 = *(const float4*)(gAf + 12);
      uint4 pa0, pa1;
      pa0.x = (u32)f2b(f0.x) | ((u32)f2b(f0.y) << 16);
      pa0.y = (u32)f2b(f0.z) | ((u32)f2b(f0.w) << 16);
      pa0.z = (u32)f2b(f1.x) | ((u32)f2b(f1.y) << 16);
      pa0.w = (u32)f2b(f1.z) | ((u32)f2b(f1.w) << 16);
      pa1.x = (u32)f2b(f2.x) | ((u32)f2b(f2.y) << 16);
      pa1.y = (u32)f2b(f2.z) | ((u32)f2b(f2.w) << 16);
      pa1.z = (u32)f2b(f3.x) | ((u32)f2b(f3.y) << 16);
      pa1.w = (u32)f2b(f3.z) | ((u32)f2b(f3.w) << 16);
      *(uint4*)&L[awo]     = pa0;
      *(uint4*)&L[awo + 8] = pa1;
      gAf += 32;
    } else {
      gll16(gA,  L + dA0); gll16(gA2, L + dA1);
      gA += 32; gA2 += 32;
    }
    gll16(gB,  L + dB0); gll16(gB2, L + dB1);
    gB += 32; gB2 += 32;
  }
  __syncthreads();

  int buf = 0;
#pragma unroll 2
  for (int kt = 0; kt < NT; ++kt) {
    // issue next-tile loads FIRST (land under this tile's MFMA body)
    float4 f0, f1, f2, f3;
    if (kt + 1 < NT) {
      u16* L = lds + (buf ^ 1) * 8192;
      if constexpr (A_FP32) {
        f0 = *(const float4*)(gAf + 0);
        f1 = *(const float4*)(gAf + 4);
        f2 = *(const float4*)(gAf + 8);
        f3 = *(const float4*)(gAf + 12);
        gAf += 32;
      } else {
        gll16(gA,  L + dA0); gll16(gA2, L + dA1);
        gA += 32; gA2 += 32;
      }
      gll16(gB,  L + dB0); gll16(gB2, L + dB1);
      gB += 32; gB2 += 32;
    }

    // MFMA body on tile kt
    {
      const u16* Lb = lds + buf * 8192;
      bf16x8 af[4], bfr[4];
#pragma unroll
      for (int fm = 0; fm < 4; ++fm)
        af[fm] = *(const bf16x8*)(Lb + aoff[fm]);
#pragma unroll
      for (int fn = 0; fn < 4; ++fn)
        bfr[fn] = *(const bf16x8*)(Lb + boff[fn]);
#pragma unroll
      for (int fm = 0; fm < 4; ++fm)
#pragma unroll
        for (int fn = 0; fn < 4; ++fn)
          acc[fm][fn] = __builtin_amdgcn_mfma_f32_16x16x32_bf16(af[fm], bfr[fn], acc[fm][fn], 0, 0, 0);
    }

    // write-late: convert + ds_write A(kt+1) into the other buffer
    if (kt + 1 < NT) {
      if constexpr (A_FP32) {
        u16* L = lds + (buf ^ 1) * 8192;
        uint4 pa0, pa1;
        pa0.x = (u32)f2b(f0.x) | ((u32)f2b(f0.y) << 16);
        pa0.y = (u32)f2b(f0.z) | ((u32)f2b(f0.w) << 16);
        pa0.z = (u32)f2b(f1.x) | ((u32)f2b(f1.y) << 16);
        pa0.w = (u32)f2b(f1.z) | ((u32)f2b(f1.w) << 16);
        pa1.x = (u32)f2b(f2.x) | ((u32)f2b(f2.y) << 16);
        pa1.y = (u32)f2b(f2.z) | ((u32)f2b(f2.w) << 16);
        pa1.z = (u32)f2b(f3.x) | ((u32)f2b(f3.y) << 16);
        pa1.w = (u32)f2b(f3.z) | ((u32)f2b(f3.w) << 16);
        *(uint4*)&L[awo]     = pa0;
        *(uint4*)&L[awo + 8] = pa1;
      }
    }

    __syncthreads();   // drains vmcnt; all waves' A ds_writes + B gll16 visible
    buf ^= 1;
  }

  // epilogue: C/D layout col=lane&15, row=(lane>>4)*4+reg  [m89-verified]
#pragma unroll
  for (int fm = 0; fm < 4; ++fm) {
#pragma unroll
    for (int fn = 0; fn < 4; ++fn) {
      int gcol = bn * 128 + wn + fn * 16 + lrow;
#pragma unroll
      for (int r = 0; r < 4; ++r) {
        int grow = bm * 128 + wm + fm * 16 + kgrp * 4 + r;
        if constexpr (OUT_FP32) {
          if (grow < MROWS)
            Cf[(size_t)grow * KD + gcol] = acc[fm][fn][r] + bias[gcol];
        } else {
          Cb[(size_t)z * MATEL + (size_t)grow * KD + gcol] = f2b(acc[fm][fn][r]);
        }
      }
    }
  }
}

// ---------------------------------------------------------------------------
// 2x2 query-tiled nearby attention (queries i>=1). One 256-thread block per
// (b, 2x2 patch tile): 4 queries x 16 heads share a 6x6+BOS = 37-key window.
// ---------------------------------------------------------------------------
__global__ __launch_bounds__(256) void k_attn_nb22(
    const u16* __restrict__ Qp, const u16* __restrict__ Kp,
    const u16* __restrict__ Vp, u16* __restrict__ AO)
{
  __shared__ float qrow[4][1024];
  __shared__ float dots[4][16][37];
  __shared__ float probs[4][16][37];
  __shared__ int   keys[37];
  __shared__ unsigned long long incm[4];

  int t = threadIdx.x;
  int b = blockIdx.x >> 8;
  int tile = blockIdx.x & 255;
  int pi0 = (tile >> 4) * 2, pj0 = (tile & 15) * 2;
  size_t rowbase = (size_t)b * 1025;

  int iq[4];
#pragma unroll
  for (int qi = 0; qi < 4; ++qi)
    iq[qi] = 1 + (pi0 + (qi >> 1)) * 32 + (pj0 + (qi & 1));

  { // stage 4 q rows as fp32
    int qi = t >> 6, off = (t & 63) * 16;
    const u16* qp = Qp + (rowbase + iq[qi]) * 1024 + off;
    uint4 a0 = *(const uint4*)qp;
    uint4 a1 = *(const uint4*)(qp + 8);
    u32 uu[8] = {a0.x, a0.y, a0.z, a0.w, a1.x, a1.y, a1.z, a1.w};
#pragma unroll
    for (int u = 0; u < 8; ++u) {
      qrow[qi][off + u * 2]     = __uint_as_float(uu[u] << 16);
      qrow[qi][off + u * 2 + 1] = __uint_as_float(uu[u] & 0xffff0000u);
    }
  }
  if (t < 37) {
    if (t < 36) {
      int r = pi0 - 2 + t / 6, c = pj0 - 2 + t % 6;
      keys[t] = (r >= 0 && r < 32 && c >= 0 && c < 32) ? (1 + r * 32 + c) : -1;
    } else {
      keys[36] = 0;  // BOS always unmasked
    }
  }
  if (t < 4) {
    int di = t >> 1, dj = t & 1;
    unsigned long long m = 1ull << 36;
    for (int j = 0; j < 36; ++j) {
      int wr = j / 6, wc = j % 6;
      if (wr >= di && wr < di + 5 && wc >= dj && wc < dj + 5) m |= 1ull << j;
    }
    incm[t] = m;
  }
  __syncthreads();

  // dots: 592 items (h,j) x 4 queries; 4 lanes cooperate per item
  int e = t & 3;
  int hD = (t >> 2) & 15;
  float qreg[4][16];
#pragma unroll
  for (int qi = 0; qi < 4; ++qi)
#pragma unroll
    for (int u = 0; u < 16; ++u)
      qreg[qi][u] = qrow[qi][hD * 64 + e * 16 + u];

#pragma unroll
  for (int p = 0; p < 10; ++p) {
    int idx = p * 64 + (t >> 2);
    float s0 = 0.f, s1 = 0.f, s2 = 0.f, s3 = 0.f;
    int key = -1;
    if (idx < 592) {
      int j = idx >> 4;
      key = keys[j];
      if (key >= 0) {
        const u16* kp = Kp + (rowbase + key) * 1024 + hD * 64 + e * 16;
        uint4 kv0 = *(const uint4*)kp;
        uint4 kv1 = *(const uint4*)(kp + 8);
        u32 uu[8] = {kv0.x, kv0.y, kv0.z, kv0.w, kv1.x, kv1.y, kv1.z, kv1.w};
#pragma unroll
        for (int u = 0; u < 8; ++u) {
          float lo = __uint_as_float(uu[u] << 16);
          float hi = __uint_as_float(uu[u] & 0xffff0000u);
          s0 += qreg[0][u * 2] * lo + qreg[0][u * 2 + 1] * hi;
          s1 += qreg[1][u * 2] * lo + qreg[1][u * 2 + 1] * hi;
          s2 += qreg[2][u * 2] * lo + qreg[2][u * 2 + 1] * hi;
          s3 += qreg[3][u * 2] * lo + qreg[3][u * 2 + 1] * hi;
        }
      }
    }
    s0 += __shfl_xor(s0, 1); s0 += __shfl_xor(s0, 2);
    s1 += __shfl_xor(s1, 1); s1 += __shfl_xor(s1, 2);
    s2 += __shfl_xor(s2, 1); s2 += __shfl_xor(s2, 2);
    s3 += __shfl_xor(s3, 1); s3 += __shfl_xor(s3, 2);
    if (idx < 592) {
      int j = idx >> 4;
      float sv = (e == 0) ? s0 : (e == 1) ? s1 : (e == 2) ? s2 : s3;
      dots[e][hD][j] = (key >= 0) ? sv * 0.125f : -3.0e38f;
    }
  }
  __syncthreads();

  { // softmax: 64 rows (qi,h) x 4 lanes each
    int row = t >> 2;
    int qi = row >> 4, hh = row & 15;
    unsigned long long inc = incm[qi];
    float dv[10];
    float m = -3.0e38f;
#pragma unroll
    for (int s = 0; s < 10; ++s) {
      int j = e + s * 4;
      float d = -3.0e38f;
      if (j < 37) {
        d = dots[qi][hh][j];
        if (!((inc >> j) & 1)) d = -3.0e38f;
      }
      dv[s] = d;
      m = fmaxf(m, d);
    }
    m = fmaxf(m, __shfl_xor(m, 1));
    m = fmaxf(m, __shfl_xor(m, 2));
    float sum = 0.f;
    float pv[10];
#pragma unroll
    for (int s = 0; s < 10; ++s) {
      int j = e + s * 4;
      float p = (j < 37) ? __expf(dv[s] - m) : 0.f;
      pv[s] = p; sum += p;
    }
    sum += __shfl_xor(sum, 1);
    sum += __shfl_xor(sum, 2);
    float inv = 1.f / sum;
#pragma unroll
    for (int s = 0; s < 10; ++s) {
      int j = e + s * 4;
      if (j < 37) probs[qi][hh][j] = pv[s] * inv;
    }
  }
  __syncthreads();

  { // PV: thread t owns dims c0=t*4 (head h=t>>4), accumulates 4 queries
    int h = t >> 4;
    int c0 = t * 4;
    float a[4][4] = {};
    for (int j = 0; j < 37; ++j) {
      int key = keys[j];
      if (key < 0) continue;
      ushort4 vv = *(const ushort4*)(Vp + (rowbase + key) * 1024 + c0);
      float v0 = b2f(vv.x), v1 = b2f(vv.y), v2 = b2f(vv.z), v3 = b2f(vv.w);
#pragma unroll
      for (int qi = 0; qi < 4; ++qi) {
        float p = probs[qi][h][j];
        a[qi][0] += p * v0; a[qi][1] += p * v1;
        a[qi][2] += p * v2; a[qi][3] += p * v3;
      }
    }
#pragma unroll
    for (int qi = 0; qi < 4; ++qi) {
      ushort4 o;
      o.x = f2b(a[qi][0]); o.y = f2b(a[qi][1]);
      o.z = f2b(a[qi][2]); o.w = f2b(a[qi][3]);
      *(ushort4*)&AO[(rowbase + iq[qi]) * 1024 + c0] = o;
    }
  }
}

// ---------------------------------------------------------------------------
// Dense attention for BOS query (i=0): attends to all 1025 keys.
// ---------------------------------------------------------------------------
__global__ __launch_bounds__(256) void k_attn_row0(
    const u16* __restrict__ Qp, const u16* __restrict__ Kp,
    const u16* __restrict__ Vp, u16* __restrict__ AO)
{
  __shared__ float q0[64];
  __shared__ float pr[1025];
  __shared__ float red[256];
  int t = threadIdx.x;
  int b = blockIdx.x >> 4, h = blockIdx.x & 15;
  size_t rowbase = (size_t)b * 1025;

  if (t < 64) q0[t] = b2f(Qp[rowbase * 1024 + h * 64 + t]);
  __syncthreads();

  float lmax = -3.0e38f;
  for (int j = t; j < 1025; j += 256) {
    const u16* kp = Kp + (rowbase + j) * 1024 + h * 64;
    float s = 0.f;
#pragma unroll
    for (int e = 0; e < 64; e += 4) {
      ushort4 kv = *(const ushort4*)(kp + e);
      s += q0[e + 0] * b2f(kv.x) + q0[e + 1] * b2f(kv.y)
         + q0[e + 2] * b2f(kv.z) + q0[e + 3] * b2f(kv.w);
    }
    s *= 0.125f;
    pr[j] = s;
    lmax = fmaxf(lmax, s);
  }
  red[t] = lmax; __syncthreads();
  for (int s = 128; s > 0; s >>= 1) {
    if (t < s) red[t] = fmaxf(red[t], red[t + s]);
    __syncthreads();
  }
  float m = red[0]; __syncthreads();

  float lsum = 0.f;
  for (int j = t; j < 1025; j += 256) {
    float p = __expf(pr[j] - m);
    pr[j] = p; lsum += p;
  }
  red[t] = lsum; __syncthreads();
  for (int s = 128; s > 0; s >>= 1) {
    if (t < s) red[t] += red[t + s];
    __syncthreads();
  }
  float inv = 1.f / red[0]; __syncthreads();

  int d = t & 63, grp = t >> 6;
  float a = 0.f;
  for (int j = grp; j < 1025; j += 4)
    a += pr[j] * b2f(Vp[(rowbase + j) * 1024 + h * 64 + d]);
  red[t] = a; __syncthreads();
  if (t < 64) {
    float tot = (red[t] + red[t + 64]) + (red[t + 128] + red[t + 192]);
    AO[rowbase * 1024 + h * 64 + t] = f2b(tot * inv);
  }
}

// ---------------------------------------------------------------------------
extern "C" void kernel_launch(void* const* d_in, const int* in_sizes, int n_in,
                              void* d_out, int out_size, void* d_ws, size_t ws_size,
                              hipStream_t stream) {
  const float* q  = (const float*)d_in[0];
  const float* k  = (const float*)d_in[1];
  const float* v  = (const float*)d_in[2];
  const float* Wq = (const float*)d_in[3];
  const float* Wk = (const float*)d_in[4];
  const float* Wv = (const float*)d_in[5];
  const float* Wo = (const float*)d_in[6];
  const float* bo = (const float*)d_in[7];
  float* out = (float*)d_out;

  // workspace (u16 units), ~143.7 MB total:
  //   wt:  4M            (Wq^T,Wk^T,Wv^T,Wo^T bf16, z-major)
  //   AO:  MATEL         (attention output bf16 padded)
  //   Qp/Kp/Vp: 3*MATEL  (projected Q,K,V bf16 padded)
  u16* wt = (u16*)d_ws;
  u16* AO = wt + (size_t)4 * 1024 * 1024;
  u16* Qp = AO + MATEL;
  u16* Kp = Qp + MATEL;
  u16* Vp = Kp + MATEL;

  k_wtrans<<<dim3(32, 32, 4), dim3(32, 8), 0, stream>>>(Wq, Wk, Wv, Wo, wt);

  // fused convert+QKV projection (A fp32, z selects q/k/v): nwg = 8*129*3
  k_gemm<true, false><<<3096, 256, 0, stream>>>(
      q, k, v, wt, Qp, nullptr, nullptr, 3096);

  // 2x2 query-tiled nearby attention: 16 b x 256 tiles = 4096 blocks
  k_attn_nb22<<<4096, 256, 0, stream>>>(Qp, Kp, Vp, AO);
  k_attn_row0<<<256, 256, 0, stream>>>(Qp, Kp, Vp, AO);

  // output projection (A bf16 = AO): nwg = 8*129 = 1032, fp32 out + bias
  k_gemm<false, true><<<1032, 256, 0, stream>>>(
      AO, nullptr, nullptr, wt + (size_t)3 * 1024 * 1024,
      nullptr, out, bo, 1032);
}

// Round 8
// 433.227 us; speedup vs baseline: 1.0902x; 1.0902x over previous
//
#include <hip/hip_runtime.h>

typedef unsigned short u16;
typedef unsigned int   u32;
typedef __attribute__((ext_vector_type(8))) __bf16 bf16x8;
typedef __attribute__((ext_vector_type(4))) float   f32x4;

#define MROWS 16400     // 16 * 1025
#define NPADROWS 16512  // padded rows in bf16 buffers
#define KD 1024
#define MATEL ((size_t)NPADROWS * KD)   // elems per padded matrix
#define NT 16           // K-tiles of 64
#define BUFSZ 16384     // u16 per buffer: A[128][64] + B[128][64]

__device__ __forceinline__ u16 f2b(float f) {
  union { float f; u32 u; } x; x.f = f;
  return (u16)((x.u + 0x7FFFu + ((x.u >> 16) & 1u)) >> 16);
}
__device__ __forceinline__ float b2f(u16 h) {
  union { u32 u; float f; } x; x.u = ((u32)h) << 16;
  return x.f;
}

__device__ __forceinline__ void gll16(const u16* g, u16* l) {
  __builtin_amdgcn_global_load_lds(
      (const __attribute__((address_space(1))) void*)g,
      (__attribute__((address_space(3))) void*)l, 16, 0, 0);
}

// ---------------------------------------------------------------------------
// Transpose + convert weights: W[k][n] f32 -> T[n][k] bf16  (z selects matrix)
// ---------------------------------------------------------------------------
__global__ __launch_bounds__(256) void k_wtrans(
    const float* __restrict__ W0, const float* __restrict__ W1,
    const float* __restrict__ W2, const float* __restrict__ W3,
    u16* __restrict__ T)
{
  __shared__ float tile[32][33];
  int z = blockIdx.z;
  const float* W = (z == 0) ? W0 : (z == 1) ? W1 : (z == 2) ? W2 : W3;
  u16* Tz = T + (size_t)z * KD * KD;
  int tx = threadIdx.x, ty = threadIdx.y;
  int k0 = blockIdx.x * 32, n0 = blockIdx.y * 32;
#pragma unroll
  for (int r = ty; r < 32; r += 8)
    tile[r][tx] = W[(size_t)(k0 + r) * KD + n0 + tx];
  __syncthreads();
#pragma unroll
  for (int r = ty; r < 32; r += 8)
    Tz[(size_t)(n0 + r) * KD + k0 + tx] = f2b(tile[tx][r]);
}

// ---------------------------------------------------------------------------
// Convert q,k,v fp32 -> padded bf16 (zero tail rows). 8 elems/thread.
// ---------------------------------------------------------------------------
__global__ __launch_bounds__(256) void k_convert(
    const float* __restrict__ q, const float* __restrict__ k,
    const float* __restrict__ v, u16* __restrict__ dst)
{
  const size_t CH_PER_MAT = MATEL / 8;
  const size_t total = 3 * CH_PER_MAT;
  for (size_t c = (size_t)blockIdx.x * 256 + threadIdx.x; c < total;
       c += (size_t)gridDim.x * 256) {
    size_t z = c / CH_PER_MAT;
    size_t r = c - z * CH_PER_MAT;
    size_t row = r >> 7;
    int col8 = (int)(r & 127) * 8;
    u16* o = dst + z * MATEL + row * KD + col8;
    if (row < MROWS) {
      const float* s = ((z == 0) ? q : (z == 1) ? k : v) + row * KD + col8;
      float4 f0 = *(const float4*)s;
      float4 f1 = *(const float4*)(s + 4);
      ushort4 o0; o0.x = f2b(f0.x); o0.y = f2b(f0.y); o0.z = f2b(f0.z); o0.w = f2b(f0.w);
      ushort4 o1; o1.x = f2b(f1.x); o1.y = f2b(f1.y); o1.z = f2b(f1.z); o1.w = f2b(f1.w);
      *(ushort4*)o = o0; *(ushort4*)(o + 4) = o1;
    } else {
      ushort4 zz; zz.x = zz.y = zz.z = zz.w = 0;
      *(ushort4*)o = zz; *(ushort4*)(o + 4) = zz;
    }
  }
}

// ---------------------------------------------------------------------------
// 2-phase prefetch bf16 MFMA GEMM, BK=64 + XOR chunk swizzle (T2 via
// pre-swizzled global source, rule-21 pattern: LINEAR gll16 dest, source
// chunk cc_log = cc_phys ^ (row&7), reads apply the same XOR).
// 128x128 tile, 4 waves 2x2, double-buffered LDS (64 KB), one
// __syncthreads per K-tile (compiler-managed drain — round-5-verified sync).
// A[NPADROWS,1024] bf16 (padded, z*MATEL); Bt[n][k] bf16 (z*1M);
// C bf16 (z*MATEL) or fp32+bias.
// ---------------------------------------------------------------------------
template<bool OUT_FP32>
__global__ __launch_bounds__(256) void k_gemm(
    const u16* __restrict__ Ab, const u16* __restrict__ Bt,
    u16* __restrict__ Cb, float* __restrict__ Cf,
    const float* __restrict__ bias, int nwg)
{
  __shared__ u16 lds[2 * BUFSZ];

  int lin = blockIdx.x;
  int cpx = nwg >> 3;                       // nwg % 8 == 0 guaranteed
  int swz = (lin & 7) * cpx + (lin >> 3);   // bijective XCD swizzle
  int bn = swz & 7;
  int rest = swz >> 3;
  int bm = rest % 129;
  int z  = rest / 129;

  int t = threadIdx.x;
  int w = t >> 6, l = t & 63;
  int lrow = l & 15, kgrp = l >> 4;
  int wm = (w >> 1) * 64, wn = (w & 1) * 64;

  // ---- staging: per buffer, 4 issues each for A and B. Issue i covers
  // rows i*32 + (t>>3), physical chunk t&7; LOGICAL col chunk is XOR'd.
  int ccl = ((t & 7) ^ ((t >> 3) & 7)) * 8;   // u16 col offset (swizzled src)
  const u16* gA[4]; const u16* gB[4];
#pragma unroll
  for (int i = 0; i < 4; ++i) {
    int prow = i * 32 + (t >> 3);
    gA[i] = Ab + (size_t)z * MATEL + (size_t)(bm * 128 + prow) * KD + ccl;
    gB[i] = Bt + (size_t)z * (1024 * 1024) + (size_t)(bn * 128 + prow) * KD + ccl;
  }
  // wave-uniform LDS dest bases (u16), HW adds lane*16B; LINEAR layout.
  // A at 0, B at 8192; issue i at i*2048 + w*512.

  // ---- fragment read offsets (u16): row*64 + ((kgrp ^ (l&7))*8); the
  // ks=1 k-sub is offset XOR 32 (chunk bit2). 2-way bank aliasing = free.
  int aoff[4], boff[4];
#pragma unroll
  for (int fm = 0; fm < 4; ++fm)
    aoff[fm] = (wm + fm * 16 + lrow) * 64 + ((kgrp ^ (l & 7)) * 8);
#pragma unroll
  for (int fn = 0; fn < 4; ++fn)
    boff[fn] = 8192 + (wn + fn * 16 + lrow) * 64 + ((kgrp ^ (l & 7)) * 8);

  f32x4 acc[4][4] = {};

#define STAGE(B) { u16* L = lds + (B) * BUFSZ;                          \
    _Pragma("unroll")                                                   \
    for (int i = 0; i < 4; ++i) { gll16(gA[i], L + i * 2048 + w * 512); gA[i] += 64; } \
    _Pragma("unroll")                                                   \
    for (int i = 0; i < 4; ++i) { gll16(gB[i], L + 8192 + i * 2048 + w * 512); gB[i] += 64; } }

  // prologue: stage tile 0 into buffer 0, drain
  STAGE(0);
  __syncthreads();

  int buf = 0;
#pragma unroll 2
  for (int kt = 0; kt < NT; ++kt) {
    if (kt + 1 < NT) STAGE(buf ^ 1);   // issue next tile FIRST (lands under MFMA)

    const u16* Lb = lds + buf * BUFSZ;
#pragma unroll
    for (int ks = 0; ks < 2; ++ks) {
      bf16x8 af[4], bfr[4];
#pragma unroll
      for (int fm = 0; fm < 4; ++fm)
        af[fm] = *(const bf16x8*)(Lb + (aoff[fm] ^ (ks << 5)));
#pragma unroll
      for (int fn = 0; fn < 4; ++fn)
        bfr[fn] = *(const bf16x8*)(Lb + (boff[fn] ^ (ks << 5)));
#pragma unroll
      for (int fm = 0; fm < 4; ++fm)
#pragma unroll
        for (int fn = 0; fn < 4; ++fn)
          acc[fm][fn] = __builtin_amdgcn_mfma_f32_16x16x32_bf16(af[fm], bfr[fn], acc[fm][fn], 0, 0, 0);
    }

    __syncthreads();   // drains vmcnt(0): next tile resident; cur reusable
    buf ^= 1;
  }
#undef STAGE

  // epilogue: C/D layout col=lane&15, row=(lane>>4)*4+reg  [m89-verified]
#pragma unroll
  for (int fm = 0; fm < 4; ++fm) {
#pragma unroll
    for (int fn = 0; fn < 4; ++fn) {
      int gcol = bn * 128 + wn + fn * 16 + lrow;
#pragma unroll
      for (int r = 0; r < 4; ++r) {
        int grow = bm * 128 + wm + fm * 16 + kgrp * 4 + r;
        if constexpr (OUT_FP32) {
          if (grow < MROWS)
            Cf[(size_t)grow * KD + gcol] = acc[fm][fn][r] + bias[gcol];
        } else {
          Cb[(size_t)z * MATEL + (size_t)grow * KD + gcol] = f2b(acc[fm][fn][r]);
        }
      }
    }
  }
}

// ---------------------------------------------------------------------------
// 2x2 query-tiled nearby attention (queries i>=1). One 256-thread block per
// (b, 2x2 patch tile): 4 queries x 16 heads share a 6x6+BOS = 37-key window.
// ---------------------------------------------------------------------------
__global__ __launch_bounds__(256) void k_attn_nb22(
    const u16* __restrict__ Qp, const u16* __restrict__ Kp,
    const u16* __restrict__ Vp, u16* __restrict__ AO)
{
  __shared__ float qrow[4][1024];
  __shared__ float dots[4][16][37];
  __shared__ float probs[4][16][37];
  __shared__ int   keys[37];
  __shared__ unsigned long long incm[4];

  int t = threadIdx.x;
  int b = blockIdx.x >> 8;
  int tile = blockIdx.x & 255;
  int pi0 = (tile >> 4) * 2, pj0 = (tile & 15) * 2;
  size_t rowbase = (size_t)b * 1025;

  int iq[4];
#pragma unroll
  for (int qi = 0; qi < 4; ++qi)
    iq[qi] = 1 + (pi0 + (qi >> 1)) * 32 + (pj0 + (qi & 1));

  { // stage 4 q rows as fp32
    int qi = t >> 6, off = (t & 63) * 16;
    const u16* qp = Qp + (rowbase + iq[qi]) * 1024 + off;
    uint4 a0 = *(const uint4*)qp;
    uint4 a1 = *(const uint4*)(qp + 8);
    u32 uu[8] = {a0.x, a0.y, a0.z, a0.w, a1.x, a1.y, a1.z, a1.w};
#pragma unroll
    for (int u = 0; u < 8; ++u) {
      qrow[qi][off + u * 2]     = __uint_as_float(uu[u] << 16);
      qrow[qi][off + u * 2 + 1] = __uint_as_float(uu[u] & 0xffff0000u);
    }
  }
  if (t < 37) {
    if (t < 36) {
      int r = pi0 - 2 + t / 6, c = pj0 - 2 + t % 6;
      keys[t] = (r >= 0 && r < 32 && c >= 0 && c < 32) ? (1 + r * 32 + c) : -1;
    } else {
      keys[36] = 0;  // BOS always unmasked
    }
  }
  if (t < 4) {
    int di = t >> 1, dj = t & 1;
    unsigned long long m = 1ull << 36;
    for (int j = 0; j < 36; ++j) {
      int wr = j / 6, wc = j % 6;
      if (wr >= di && wr < di + 5 && wc >= dj && wc < dj + 5) m |= 1ull << j;
    }
    incm[t] = m;
  }
  __syncthreads();

  // dots: 592 items (h,j) x 4 queries; 4 lanes cooperate per item
  int e = t & 3;
  int hD = (t >> 2) & 15;
  float qreg[4][16];
#pragma unroll
  for (int qi = 0; qi < 4; ++qi)
#pragma unroll
    for (int u = 0; u < 16; ++u)
      qreg[qi][u] = qrow[qi][hD * 64 + e * 16 + u];

#pragma unroll
  for (int p = 0; p < 10; ++p) {
    int idx = p * 64 + (t >> 2);
    float s0 = 0.f, s1 = 0.f, s2 = 0.f, s3 = 0.f;
    int key = -1;
    if (idx < 592) {
      int j = idx >> 4;
      key = keys[j];
      if (key >= 0) {
        const u16* kp = Kp + (rowbase + key) * 1024 + hD * 64 + e * 16;
        uint4 kv0 = *(const uint4*)kp;
        uint4 kv1 = *(const uint4*)(kp + 8);
        u32 uu[8] = {kv0.x, kv0.y, kv0.z, kv0.w, kv1.x, kv1.y, kv1.z, kv1.w};
#pragma unroll
        for (int u = 0; u < 8; ++u) {
          float lo = __uint_as_float(uu[u] << 16);
          float hi = __uint_as_float(uu[u] & 0xffff0000u);
          s0 += qreg[0][u * 2] * lo + qreg[0][u * 2 + 1] * hi;
          s1 += qreg[1][u * 2] * lo + qreg[1][u * 2 + 1] * hi;
          s2 += qreg[2][u * 2] * lo + qreg[2][u * 2 + 1] * hi;
          s3 += qreg[3][u * 2] * lo + qreg[3][u * 2 + 1] * hi;
        }
      }
    }
    s0 += __shfl_xor(s0, 1); s0 += __shfl_xor(s0, 2);
    s1 += __shfl_xor(s1, 1); s1 += __shfl_xor(s1, 2);
    s2 += __shfl_xor(s2, 1); s2 += __shfl_xor(s2, 2);
    s3 += __shfl_xor(s3, 1); s3 += __shfl_xor(s3, 2);
    if (idx < 592) {
      int j = idx >> 4;
      float sv = (e == 0) ? s0 : (e == 1) ? s1 : (e == 2) ? s2 : s3;
      dots[e][hD][j] = (key >= 0) ? sv * 0.125f : -3.0e38f;
    }
  }
  __syncthreads();

  { // softmax: 64 rows (qi,h) x 4 lanes each
    int row = t >> 2;
    int qi = row >> 4, hh = row & 15;
    unsigned long long inc = incm[qi];
    float dv[10];
    float m = -3.0e38f;
#pragma unroll
    for (int s = 0; s < 10; ++s) {
      int j = e + s * 4;
      float d = -3.0e38f;
      if (j < 37) {
        d = dots[qi][hh][j];
        if (!((inc >> j) & 1)) d = -3.0e38f;
      }
      dv[s] = d;
      m = fmaxf(m, d);
    }
    m = fmaxf(m, __shfl_xor(m, 1));
    m = fmaxf(m, __shfl_xor(m, 2));
    float sum = 0.f;
    float pv[10];
#pragma unroll
    for (int s = 0; s < 10; ++s) {
      int j = e + s * 4;
      float p = (j < 37) ? __expf(dv[s] - m) : 0.f;
      pv[s] = p; sum += p;
    }
    sum += __shfl_xor(sum, 1);
    sum += __shfl_xor(sum, 2);
    float inv = 1.f / sum;
#pragma unroll
    for (int s = 0; s < 10; ++s) {
      int j = e + s * 4;
      if (j < 37) probs[qi][hh][j] = pv[s] * inv;
    }
  }
  __syncthreads();

  { // PV: thread t owns dims c0=t*4 (head h=t>>4), accumulates 4 queries
    int h = t >> 4;
    int c0 = t * 4;
    float a[4][4] = {};
    for (int j = 0; j < 37; ++j) {
      int key = keys[j];
      if (key < 0) continue;
      ushort4 vv = *(const ushort4*)(Vp + (rowbase + key) * 1024 + c0);
      float v0 = b2f(vv.x), v1 = b2f(vv.y), v2 = b2f(vv.z), v3 = b2f(vv.w);
#pragma unroll
      for (int qi = 0; qi < 4; ++qi) {
        float p = probs[qi][h][j];
        a[qi][0] += p * v0; a[qi][1] += p * v1;
        a[qi][2] += p * v2; a[qi][3] += p * v3;
      }
    }
#pragma unroll
    for (int qi = 0; qi < 4; ++qi) {
      ushort4 o;
      o.x = f2b(a[qi][0]); o.y = f2b(a[qi][1]);
      o.z = f2b(a[qi][2]); o.w = f2b(a[qi][3]);
      *(ushort4*)&AO[(rowbase + iq[qi]) * 1024 + c0] = o;
    }
  }
}

// ---------------------------------------------------------------------------
// Dense attention for BOS query (i=0): attends to all 1025 keys.
// ---------------------------------------------------------------------------
__global__ __launch_bounds__(256) void k_attn_row0(
    const u16* __restrict__ Qp, const u16* __restrict__ Kp,
    const u16* __restrict__ Vp, u16* __restrict__ AO)
{
  __shared__ float q0[64];
  __shared__ float pr[1025];
  __shared__ float red[256];
  int t = threadIdx.x;
  int b = blockIdx.x >> 4, h = blockIdx.x & 15;
  size_t rowbase = (size_t)b * 1025;

  if (t < 64) q0[t] = b2f(Qp[rowbase * 1024 + h * 64 + t]);
  __syncthreads();

  float lmax = -3.0e38f;
  for (int j = t; j < 1025; j += 256) {
    const u16* kp = Kp + (rowbase + j) * 1024 + h * 64;
    float s = 0.f;
#pragma unroll
    for (int e = 0; e < 64; e += 4) {
      ushort4 kv = *(const ushort4*)(kp + e);
      s += q0[e + 0] * b2f(kv.x) + q0[e + 1] * b2f(kv.y)
         + q0[e + 2] * b2f(kv.z) + q0[e + 3] * b2f(kv.w);
    }
    s *= 0.125f;
    pr[j] = s;
    lmax = fmaxf(lmax, s);
  }
  red[t] = lmax; __syncthreads();
  for (int s = 128; s > 0; s >>= 1) {
    if (t < s) red[t] = fmaxf(red[t], red[t + s]);
    __syncthreads();
  }
  float m = red[0]; __syncthreads();

  float lsum = 0.f;
  for (int j = t; j < 1025; j += 256) {
    float p = __expf(pr[j] - m);
    pr[j] = p; lsum += p;
  }
  red[t] = lsum; __syncthreads();
  for (int s = 128; s > 0; s >>= 1) {
    if (t < s) red[t] += red[t + s];
    __syncthreads();
  }
  float inv = 1.f / red[0]; __syncthreads();

  int d = t & 63, grp = t >> 6;
  float a = 0.f;
  for (int j = grp; j < 1025; j += 4)
    a += pr[j] * b2f(Vp[(rowbase + j) * 1024 + h * 64 + d]);
  red[t] = a; __syncthreads();
  if (t < 64) {
    float tot = (red[t] + red[t + 64]) + (red[t + 128] + red[t + 192]);
    AO[rowbase * 1024 + h * 64 + t] = f2b(tot * inv);
  }
}

// ---------------------------------------------------------------------------
extern "C" void kernel_launch(void* const* d_in, const int* in_sizes, int n_in,
                              void* d_out, int out_size, void* d_ws, size_t ws_size,
                              hipStream_t stream) {
  const float* q  = (const float*)d_in[0];
  const float* k  = (const float*)d_in[1];
  const float* v  = (const float*)d_in[2];
  const float* Wq = (const float*)d_in[3];
  const float* Wk = (const float*)d_in[4];
  const float* Wv = (const float*)d_in[5];
  const float* Wo = (const float*)d_in[6];
  const float* bo = (const float*)d_in[7];
  float* out = (float*)d_out;

  // workspace (u16 units), ~211.3 MB total:
  //   wt:  4M            (Wq^T,Wk^T,Wv^T,Wo^T bf16)
  //   qb:  3*MATEL       (q,k,v converted padded bf16)  [AO aliases qb]
  //   Qp:  3*MATEL       (projected Q,K,V bf16 padded)
  u16* wt = (u16*)d_ws;
  u16* qb = wt + (size_t)4 * 1024 * 1024;
  u16* Qp = qb + 3 * MATEL;
  u16* Kp = Qp + MATEL;
  u16* Vp = Kp + MATEL;
  u16* AO = qb;  // alias: qb dead after projection GEMM

  k_wtrans<<<dim3(32, 32, 4), dim3(32, 8), 0, stream>>>(Wq, Wk, Wv, Wo, wt);
  k_convert<<<2048, 256, 0, stream>>>(q, k, v, qb);

  // Q/K/V projections (z = 0,1,2 via grid decode): nwg = 8*129*3 = 3096
  k_gemm<false><<<3096, 256, 0, stream>>>(qb, wt, Qp, nullptr, nullptr, 3096);

  // 2x2 query-tiled nearby attention: 16 b x 256 tiles = 4096 blocks
  k_attn_nb22<<<4096, 256, 0, stream>>>(Qp, Kp, Vp, AO);
  k_attn_row0<<<256, 256, 0, stream>>>(Qp, Kp, Vp, AO);

  // output projection: nwg = 8*129 = 1032, fp32 out + bias
  k_gemm<true><<<1032, 256, 0, stream>>>(AO, wt + (size_t)3 * 1024 * 1024,
                                         nullptr, out, bo, 1032);
}